// Round 3
// baseline (8023.644 us; speedup 1.0000x reference)
//
#include <hip/hip_runtime.h>

#define NN 64
#define LDP (NN + 1)  // +1 padding: kills the 32/64-way column-access bank conflicts

// Deflation tolerance: float-storage T has a subdiagonal noise floor of
// ~1.2e-7 * local scale; 5e-7 is ~4x above it (proven R1/R2: absmax 0.03125).
#define DEFL_TOL 5e-7

// Packed upper-Hessenberg band with 3 subdiagonals. Row r stores cols
// max(0,r-3)..63. 2266 floats = 9064 B.
#define BAND_SIZE 2266

__device__ __forceinline__ int rb_of(int r) {
  int t = (r >= 4) ? (((r - 4) * (r - 3)) >> 1) : 0;
  int s = (r >= 3) ? (r - 3) : 0;
  return 64 * r - t - s;
}

__device__ __forceinline__ double guard_d(double p) {
  if (fabs(p) < 1e-280) return (p >= 0.0) ? 1e-280 : -1e-280;
  return p;
}

// Wave-uniform lane read of a double via v_readlane (no LDS, no lgkmcnt).
__device__ __forceinline__ double readlane_d(double v, int l) {
  union { double d; int i[2]; } u;
  u.d = v;
  int a = __builtin_amdgcn_readlane(u.i[0], l);
  int b = __builtin_amdgcn_readlane(u.i[1], l);
  union { double d; int i[2]; } w;
  w.i[0] = a; w.i[1] = b;
  return w.d;
}

// Single-wave workgroup fences. A 64-thread block is ONE wave: s_barrier is
// unnecessary; cross-lane LDS visibility needs only lgkmcnt(0) (DS ops are
// in-order per wave) + a compiler "memory" clobber. sched_barrier(0) stops
// hipcc hoisting dependent ops past the inline-asm waitcnt (rule #18).
// __syncthreads would add s_waitcnt vmcnt(0) — a global-store drain on the
// serial chain, twice per bulge-chase step: the R2 bottleneck.
#define WAVE_FENCE()                                   \
  do {                                                 \
    asm volatile("s_waitcnt lgkmcnt(0)" ::: "memory"); \
    __builtin_amdgcn_sched_barrier(0);                 \
  } while (0)
#define VM_FENCE()                                     \
  do {                                                 \
    asm volatile("s_waitcnt vmcnt(0)" ::: "memory");   \
    __builtin_amdgcn_sched_barrier(0);                 \
  } while (0)

// ============================================================================
// Kernel 1: Hessenberg reduction. FLOAT-storage T in LDS, DOUBLE math.
// Single-wave fences instead of __syncthreads; one vmcnt(0) per k (the Q
// global RMW hazard across iterations) instead of three full drains.
// LDS 17152 B -> 9 blocks/CU.
// ============================================================================
__global__ __launch_bounds__(64) void hess64_kernel(const float* __restrict__ x,
                                                    float* __restrict__ out,
                                                    float* __restrict__ ws) {
  __shared__ float Td[NN][LDP];
  __shared__ double vbuf[NN];

  const int lane = threadIdx.x;
  const size_t mat = blockIdx.x;
  const float* src = x + mat * NN * NN;
  float* Qg = out + mat * NN * NN;  // Q^T layout: Qg[c*64+r] = Q[r][c]
  float* Tg = ws + mat * NN * NN;

  for (int r = 0; r < NN; ++r) Td[r][lane] = src[r * NN + lane];
  for (int c = 0; c < NN; ++c) Qg[c * NN + lane] = (c == lane) ? 1.0f : 0.0f;
  WAVE_FENCE();

  for (int k = 0; k <= NN - 3; ++k) {
    const int m = NN - 1 - k;
    double xt = (lane < m) ? (double)Td[k + 1 + lane][k] : 0.0;
    double ss = xt * xt;
    #pragma unroll
    for (int off = 32; off; off >>= 1) ss += __shfl_xor(ss, off);
    double x0 = (double)Td[k + 1][k];
    if (ss > 1e-280) {  // uniform across wave
      double sg = sqrt(ss);
      double beta = (x0 >= 0.0) ? -sg : sg;
      double tau = 1.0 / (ss - beta * x0);
      vbuf[lane] = (lane < m) ? (xt - ((lane == 0) ? beta : 0.0)) : 0.0;
      WAVE_FENCE();
      if (lane >= k + 1) {  // left apply
        const int j = lane;
        double acc = 0.0;
        for (int t = 0; t < m; ++t) acc += vbuf[t] * (double)Td[k + 1 + t][j];
        acc *= tau;
        for (int t = 0; t < m; ++t)
          Td[k + 1 + t][j] = (float)((double)Td[k + 1 + t][j] - vbuf[t] * acc);
      }
      WAVE_FENCE();
      // exact zeros below subdiagonal (col k) — parallel across lanes
      // (col k is disjoint from the right apply's cols k+1..)
      if (lane == 0) Td[k + 1][k] = (float)beta;
      if (lane >= 1 && lane < m) Td[k + 1 + lane][k] = 0.0f;
      VM_FENCE();  // Q RMW: iteration k-1's stores vs this iteration's loads
      {  // right apply on T (LDS) and Q (global, coalesced, DOUBLE math)
        const int r = lane;
        double acc = 0.0;
        double qa = 0.0;
        for (int t = 0; t < m; ++t) {
          double vt = vbuf[t];
          acc += (double)Td[r][k + 1 + t] * vt;
          qa += (double)Qg[(k + 1 + t) * NN + r] * vt;
        }
        acc *= tau;
        qa *= tau;
        for (int t = 0; t < m; ++t) {
          double vt = vbuf[t];
          Td[r][k + 1 + t] = (float)((double)Td[r][k + 1 + t] - acc * vt);
          Qg[(k + 1 + t) * NN + r] =
              (float)((double)Qg[(k + 1 + t) * NN + r] - qa * vt);
        }
      }
      WAVE_FENCE();
    }
  }

  for (int r = 0; r < NN; ++r) Tg[r * NN + lane] = Td[r][lane];
}

// ============================================================================
// Kernel 2: Francis double-shift QR on packed band. Single-wave fences (no
// vmcnt drains on the chase chain) + DEFERRED Q: the chase stashes each
// reflector normalized as (tau*v0^2, v1/v0, v2/v0) — all O(1)-bounded,
// float-safe (|vi/v0| <= 1, tau' in [1,2]; the raw tau/v NaN hazard only
// exists unnormalized) — then a fence-free register-window loop applies the
// whole sweep to Q with ONE vmcnt(0) per sweep instead of two per step.
// LDS 9064 + 772 B -> 16 blocks/CU (grid-capped anyway at 4096/256 = 16).
// ============================================================================
#define TD(r, c) band[rb_of(r) + (c)]

__global__ __launch_bounds__(64) void qr64_kernel(float* __restrict__ out,
                                                  float* __restrict__ ws) {
  __shared__ float band[BAND_SIZE];
  __shared__ float recT[NN], recY[NN], recZ[NN];  // normalized reflector stash

  const int lane = threadIdx.x;
  const size_t mat = blockIdx.x;
  float* Qg = out + mat * NN * NN;
  float* Tg = ws + mat * NN * NN;

  // dense H -> band
  for (int r = 0; r < NN; ++r) {
    int st = (r >= 3) ? (r - 3) : 0;
    if (lane >= st) band[rb_of(r) + lane] = Tg[r * NN + lane];
  }
  WAVE_FENCE();

  int hi = NN - 1;
  int its = 0, total = 0;
  while (hi > 0) {
    bool small = false;
    if (lane >= 1 && lane <= hi) {
      double s = fabs((double)TD(lane - 1, lane - 1)) + fabs((double)TD(lane, lane));
      if (s == 0.0) s = 1e-300;
      small = fabs((double)TD(lane, lane - 1)) <= DEFL_TOL * s;
    }
    unsigned long long msk = __ballot(small) | 1ULL;
    if (hi < 63) msk &= (2ULL << hi) - 1ULL;
    const int lo = 63 - __clzll(msk);
    if (lo > 0) {
      if (lane == 0) TD(lo, lo - 1) = 0.0f;
      WAVE_FENCE();
    }
    if (lo == hi) { hi -= 1; its = 0; continue; }
    if (lo == hi - 1) {  // 2x2 window
      double a = TD(hi - 1, hi - 1), b = TD(hi - 1, hi);
      double c = TD(hi, hi - 1), d = TD(hi, hi);
      double pp = 0.5 * (a - d);
      double disc = pp * pp + b * c;
      if (disc >= 0.0) {  // real pair: rotate to triangular
        double sq = sqrt(disc);
        double mid = 0.5 * (a + d);
        double lam = mid + ((mid >= 0.0) ? sq : -sq);
        double u0 = b, u1 = lam - a;
        double w0 = lam - d, w1 = c;
        double nu = u0 * u0 + u1 * u1, nw = w0 * w0 + w1 * w1;
        double cs, sn;
        if (nu >= nw && nu > 1e-280) { double n2 = sqrt(nu); cs = u0 / n2; sn = u1 / n2; }
        else if (nw > 1e-280) { double n2 = sqrt(nw); cs = w0 / n2; sn = w1 / n2; }
        else { cs = 1.0; sn = 0.0; }
        {
          const int j = lane;
          const int jmin = (hi >= 2) ? (hi - 2) : 0;  // cols < hi-2 exact 0
          if (j >= jmin) {
            double r0 = TD(hi - 1, j), r1 = TD(hi, j);
            TD(hi - 1, j) = (float)(cs * r0 + sn * r1);
            TD(hi, j) = (float)(cs * r1 - sn * r0);
          }
        }
        WAVE_FENCE();
        {
          const int r = lane;
          if (r <= hi) {
            double c0 = TD(r, hi - 1), c1 = TD(r, hi);
            TD(r, hi - 1) = (float)(cs * c0 + sn * c1);
            TD(r, hi) = (float)(cs * c1 - sn * c0);
          }
        }
        VM_FENCE();  // drain prior sweep's deferred-Q stores before Q loads
        {
          const int r = lane;
          double q0 = (double)Qg[(hi - 1) * NN + r], q1 = (double)Qg[hi * NN + r];
          Qg[(hi - 1) * NN + r] = (float)(cs * q0 + sn * q1);
          Qg[hi * NN + r] = (float)(cs * q1 - sn * q0);
        }
        WAVE_FENCE();
        if (lane == 0) TD(hi, hi - 1) = 0.0f;
        WAVE_FENCE();
      }
      hi -= 2; its = 0; continue;
    }
    ++its; ++total;
    if (its > 40 || total > 2000) {  // safety: force deflation
      if (lane == 0) TD(hi, hi - 1) = 0.0f;
      WAVE_FENCE();
      hi -= 1; its = 0; continue;
    }
    double sa, sb, sc2, sd2;
    if (its == 10 || its == 20 || its == 30) {  // exceptional shift
      double sx = fabs((double)TD(hi, hi - 1)) + fabs((double)TD(hi - 1, hi - 2));
      sa = 0.75 * sx + (double)TD(hi, hi); sb = -0.4375 * sx; sc2 = sx; sd2 = sa;
    } else {
      sa = TD(hi - 1, hi - 1); sb = TD(hi - 1, hi);
      sc2 = TD(hi, hi - 1); sd2 = TD(hi, hi);
    }
    double tr = sa + sd2;
    double det = sa * sd2 - sb * sc2;
    double h11 = TD(lo, lo), h12 = TD(lo, lo + 1), h21 = TD(lo + 1, lo);
    double h22 = TD(lo + 1, lo + 1), h32 = TD(lo + 2, lo + 1);
    double cvx = h11 * h11 + h12 * h21 - tr * h11 + det;
    double cvy = h21 * (h11 + h22 - tr);
    double cvz = h21 * h32;

    int nk = hi - lo;  // reflectors recorded this sweep (uniform register)
    for (int k = lo; k <= hi - 1; ++k) {  // bulge chase — T only, no Q
      const int nr = (k + 2 <= hi) ? 3 : 2;
      const double vx = cvx, vy = cvy, vz = (nr == 3) ? cvz : 0.0;
      double ss2 = vx * vx + vy * vy + vz * vz;
      if (ss2 < 1e-280) { nk = k - lo; break; }  // bulge collapsed
      double sg = sqrt(ss2);
      double beta = (vx >= 0.0) ? -sg : sg;
      double v0 = vx - beta, v1 = vy, v2 = vz;
      double tau = 1.0 / (ss2 - beta * vx);
      if (lane == 0) {  // stash normalized reflector (uniform values)
        double iv0 = 1.0 / v0;  // |v0| >= sg > 0 here
        recT[k - lo] = (float)(tau * v0 * v0);
        recY[k - lo] = (float)(v1 * iv0);
        recZ[k - lo] = (float)(v2 * iv0);
      }
      const int jlo = (k > lo) ? k : lo;
      if (lane >= jlo) {  // left apply
        const int j = lane;
        double t0 = TD(k, j), t1 = TD(k + 1, j);
        double t2v = (nr == 3) ? (double)TD(k + 2, j) : 0.0;
        double tt = tau * (v0 * t0 + v1 * t1 + v2 * t2v);
        TD(k, j) = (float)(t0 - v0 * tt);
        TD(k + 1, j) = (float)(t1 - v1 * tt);
        if (nr == 3) TD(k + 2, j) = (float)(t2v - v2 * tt);
      }
      WAVE_FENCE();
      if (lane == 0 && k > lo) {  // exact bulge zeros (col k-1)
        TD(k, k - 1) = (float)beta;
        TD(k + 1, k - 1) = 0.0f;
        if (nr == 3) TD(k + 2, k - 1) = 0.0f;
      }
      const int rmax = (k + 3 <= hi) ? (k + 3) : hi;
      double n0 = 0.0, n1 = 0.0, n2 = 0.0;
      if (lane <= rmax) {  // right apply
        double c0 = TD(lane, k), c1 = TD(lane, k + 1);
        double c2v = (nr == 3) ? (double)TD(lane, k + 2) : 0.0;
        double tt = tau * (c0 * v0 + c1 * v1 + c2v * v2);
        n0 = c0 - tt * v0;
        n1 = c1 - tt * v1;
        n2 = c2v - tt * v2;
      }
      {  // register handoff of next bulge column (DOUBLE, never rounded)
        const int ly = (k + 2 <= 63) ? (k + 2) : 0;
        const int lz = (k + 3 <= hi) ? (k + 3) : 0;
        cvx = readlane_d(n0, k + 1);
        cvy = readlane_d(n0, ly);
        cvz = readlane_d(n0, lz);
      }
      if (lane <= rmax) {
        TD(lane, k) = (float)n0;
        TD(lane, k + 1) = (float)n1;
        if (nr == 3) TD(lane, k + 2) = (float)n2;
      }
      WAVE_FENCE();
    }

    // ---- deferred Q apply: fence-free register window, 1 vmcnt per sweep ----
    VM_FENCE();  // drain prior Q stores before reloading the window
    {
      double qw0 = (double)Qg[lo * NN + lane];
      double qw1 = (double)Qg[(lo + 1) * NN + lane];
      double qw2 = (double)Qg[(lo + 2) * NN + lane];
      for (int i = 0; i < nk; ++i) {
        const int k = lo + i;
        double tq = (double)recT[i];
        double r1 = (double)recY[i];
        double r2 = (double)recZ[i];
        double qnext = (k + 3 <= hi) ? (double)Qg[(k + 3) * NN + lane] : 0.0;
        double t = tq * (qw0 + qw1 * r1 + qw2 * r2);
        qw0 -= t;
        qw1 -= t * r1;
        qw2 -= t * r2;
        Qg[k * NN + lane] = (float)qw0;  // col k final for this sweep
        qw0 = qw1; qw1 = qw2; qw2 = qnext;
      }
      if (nk == hi - lo) {
        Qg[hi * NN + lane] = (float)qw0;  // flush last window col
      } else {  // collapsed at k = lo+nk: flush pending window cols
        const int k = lo + nk;
        Qg[k * NN + lane] = (float)qw0;
        Qg[(k + 1) * NN + lane] = (float)qw1;
        if (k + 2 <= hi) Qg[(k + 2) * NN + lane] = (float)qw2;
      }
    }
  }
  WAVE_FENCE();

  // band -> dense Schur T (subdiag + upper only)
  for (int r = 0; r < NN; ++r) {
    float v = 0.0f;
    int st = (r >= 1) ? (r - 1) : 0;
    if (lane >= st) v = band[rb_of(r) + lane];
    Tg[r * NN + lane] = v;
  }
}

// ============================================================================
// Kernel 3: Parlett recurrence + symmetrize + Q Fs Q^T. 256 threads, 4-thread
// group per Sylvester pair, block-start table. Unchanged from R2 (proven).
// ============================================================================
__global__ __launch_bounds__(256) void parlett64_kernel(const float* __restrict__ ws,
                                                        float* __restrict__ out) {
  __shared__ float Tfbuf[NN * LDP];
  __shared__ float Fbuf[NN * LDP];
  __shared__ int blkstart[NN];
  __shared__ int bi_of[NN];
  float* Tf = Tfbuf;
  float* Fp = Fbuf;

  const int tid = threadIdx.x;
  const int w = tid >> 6;
  const int lane = tid & 63;
  const size_t mat = blockIdx.x;
  const float* Tg = ws + mat * NN * NN;
  float* dst = out + mat * NN * NN;
  float* Qg = dst;

  #define TF(r, c) ((double)Tf[(r) * LDP + (c)])
  #define FF(r, c) Fp[(r) * LDP + (c)]

  for (int r = w; r < NN; r += 4) Tf[r * LDP + lane] = Tg[r * NN + lane];
  __syncthreads();

  unsigned long long pair_mask =
      __ballot((lane < NN - 1) && (Tf[(lane + 1) * LDP + lane] != 0.0f));
  unsigned long long start_mask = ~(pair_mask << 1);
  const bool isstart = (start_mask >> lane) & 1ULL;
  const bool ispair = (pair_mask >> lane) & 1ULL;
  double fdiag = 0.0, mymod = 1e300;
  if (isstart) {
    if (ispair) {
      double a = TF(lane, lane), b = TF(lane, lane + 1);
      double c = TF(lane + 1, lane), d = TF(lane + 1, lane + 1);
      fdiag = sqrt(fmax(a * d - b * c, 0.0));
    } else {
      fdiag = fabs(TF(lane, lane));
    }
    mymod = fdiag;
  }
  #pragma unroll
  for (int off = 32; off; off >>= 1) mymod = fmin(mymod, __shfl_xor(mymod, off));
  const double cshift = 1e-6 * mymod;

  if (tid < NN) {
    int nb = (int)__popcll(start_mask & ((1ULL << lane) - 1ULL));
    bi_of[lane] = nb;
    if (isstart) blkstart[nb] = lane;
  }
  for (int r = w; r < NN; r += 4) FF(r, lane) = 0.0f;
  __syncthreads();
  if (tid < NN && isstart) {
    FF(lane, lane) = (float)fdiag;
    if (ispair) FF(lane + 1, lane + 1) = (float)fdiag;
  }
  __syncthreads();

  const int sub = lane & 3;
  const int si = (lane & ~3) | w;

  for (int dist = 1; dist < NN; ++dist) {
    const int sj = si + dist;
    bool active = (sj < NN) && ((start_mask >> si) & 1ULL) && ((start_mask >> sj) & 1ULL);
    if (active) {
      const int p = ((pair_mask >> si) & 1ULL) ? 2 : 1;
      const int q = ((pair_mask >> sj) & 1ULL) ? 2 : 1;
      const int bi0 = bi_of[si], bi1 = bi_of[sj];
      double c00 = 0, c01 = 0, c10 = 0, c11 = 0;
      for (int b = bi0 + sub; b < bi1; b += 4) {
        const int k = blkstart[b];
        const bool kp = (pair_mask >> k) & 1ULL;
        double f00 = FF(si, k);
        double f01 = kp ? (double)FF(si, k + 1) : 0.0;
        double f10 = (p == 2) ? (double)FF(si + 1, k) : 0.0;
        double f11 = (p == 2 && kp) ? (double)FF(si + 1, k + 1) : 0.0;
        double t00 = TF(k, sj);
        double t01 = (q == 2) ? TF(k, sj + 1) : 0.0;
        double t10 = kp ? TF(k + 1, sj) : 0.0;
        double t11 = (kp && q == 2) ? TF(k + 1, sj + 1) : 0.0;
        c00 += f00 * t00 + f01 * t10;
        c01 += f00 * t01 + f01 * t11;
        c10 += f10 * t00 + f11 * t10;
        c11 += f10 * t01 + f11 * t11;
      }
      for (int b = bi0 + 1 + sub; b <= bi1; b += 4) {
        const int k = blkstart[b];
        const bool kp = (pair_mask >> k) & 1ULL;
        double t00 = TF(si, k);
        double t01 = kp ? TF(si, k + 1) : 0.0;
        double t10 = (p == 2) ? TF(si + 1, k) : 0.0;
        double t11 = (p == 2 && kp) ? TF(si + 1, k + 1) : 0.0;
        double f00 = FF(k, sj);
        double f01 = (q == 2) ? (double)FF(k, sj + 1) : 0.0;
        double f10 = kp ? (double)FF(k + 1, sj) : 0.0;
        double f11 = (kp && q == 2) ? (double)FF(k + 1, sj + 1) : 0.0;
        c00 -= t00 * f00 + t01 * f10;
        c01 -= t00 * f01 + t01 * f11;
        c10 -= t10 * f00 + t11 * f10;
        c11 -= t10 * f01 + t11 * f11;
      }
      c00 += __shfl_xor(c00, 1); c00 += __shfl_xor(c00, 2);
      c01 += __shfl_xor(c01, 1); c01 += __shfl_xor(c01, 2);
      c10 += __shfl_xor(c10, 1); c10 += __shfl_xor(c10, 2);
      c11 += __shfl_xor(c11, 1); c11 += __shfl_xor(c11, 2);
      if (sub == 0) {
        double x00 = 0, x01 = 0, x10 = 0, x11 = 0;
        if (p == 1 && q == 1) {
          x00 = c00 / guard_d(TF(si, si) - TF(sj, sj));
        } else if (p == 2 && q == 1) {
          double t = TF(sj, sj);
          double m00 = TF(si, si) - t, m01 = TF(si, si + 1);
          double m10 = TF(si + 1, si), m11 = TF(si + 1, si + 1) - t;
          double dd = guard_d(m00 * m11 - m01 * m10);
          x00 = (m11 * c00 - m01 * c10) / dd;
          x10 = (m00 * c10 - m10 * c00) / dd;
        } else if (p == 1 && q == 2) {
          double t = TF(si, si);
          double m00 = t - TF(sj, sj), m01 = -TF(sj, sj + 1);
          double m10 = -TF(sj + 1, sj), m11 = t - TF(sj + 1, sj + 1);
          double dd = guard_d(m00 * m11 - m01 * m10);
          x00 = (c00 * m11 - c01 * m10) / dd;
          x01 = (c01 * m00 - c00 * m01) / dd;
        } else {
          double A00 = TF(si, si), A01 = TF(si, si + 1);
          double A10 = TF(si + 1, si), A11 = TF(si + 1, si + 1);
          double B00 = TF(sj, sj), B01 = TF(sj, sj + 1);
          double B10 = TF(sj + 1, sj), B11 = TF(sj + 1, sj + 1);
          double M[4][5] = {
              {A00 - B00, A01, -B10, 0.0, c00},
              {A10, A11 - B00, 0.0, -B10, c10},
              {-B01, 0.0, A00 - B11, A01, c01},
              {0.0, -B01, A10, A11 - B11, c11}};
          #pragma unroll
          for (int cc = 0; cc < 4; ++cc) {
            #pragma unroll
            for (int rr2 = cc + 1; rr2 < 4; ++rr2) {
              bool sw = fabs(M[rr2][cc]) > fabs(M[cc][cc]);
              #pragma unroll
              for (int t2 = cc; t2 < 5; ++t2) {
                double aa = M[cc][t2], bb = M[rr2][t2];
                M[cc][t2] = sw ? bb : aa;
                M[rr2][t2] = sw ? aa : bb;
              }
            }
            double inv = 1.0 / guard_d(M[cc][cc]);
            #pragma unroll
            for (int rr2 = cc + 1; rr2 < 4; ++rr2) {
              double f2 = M[rr2][cc] * inv;
              #pragma unroll
              for (int t2 = cc; t2 < 5; ++t2) M[rr2][t2] -= f2 * M[cc][t2];
            }
          }
          double z3 = M[3][4] / guard_d(M[3][3]);
          double z2 = (M[2][4] - M[2][3] * z3) / guard_d(M[2][2]);
          double z1 = (M[1][4] - M[1][3] * z3 - M[1][2] * z2) / guard_d(M[1][1]);
          double z0 = (M[0][4] - M[0][3] * z3 - M[0][2] * z2 - M[0][1] * z1) / guard_d(M[0][0]);
          x00 = z0; x10 = z1; x01 = z2; x11 = z3;
        }
        FF(si, sj) = (float)x00;
        if (q == 2) FF(si, sj + 1) = (float)x01;
        if (p == 2) {
          FF(si + 1, sj) = (float)x10;
          if (q == 2) FF(si + 1, sj + 1) = (float)x11;
        }
      }
    }
    __syncthreads();
  }

  {
    const int r = lane;
    for (int j = r + 1 + w; j < NN; j += 4) {
      float v = 0.5f * (FF(r, j) + FF(j, r));
      FF(r, j) = v;
      FF(j, r) = v;
    }
    if (w == 0) FF(r, r) += (float)cshift;
  }
  __syncthreads();

  float* Qs = Tf;  // T dead after Parlett
  for (int c = w; c < NN; c += 4) Qs[lane * LDP + c] = Qg[c * NN + lane];
  __syncthreads();

  float acc[16];
  const int r0 = w * 16;
  #pragma unroll
  for (int i = 0; i < 16; ++i) acc[i] = 0.0f;
  for (int k = 0; k < NN; ++k) {
    float f = FF(k, lane);
    #pragma unroll
    for (int i = 0; i < 16; ++i) acc[i] += Qs[(r0 + i) * LDP + k] * f;
  }
  __syncthreads();
  float* W = Fp;
  #pragma unroll
  for (int i = 0; i < 16; ++i) W[(r0 + i) * LDP + lane] = acc[i];
  __syncthreads();

  #pragma unroll
  for (int i = 0; i < 16; ++i) acc[i] = 0.0f;
  for (int k = 0; k < NN; ++k) {
    float qv = Qs[lane * LDP + k];
    #pragma unroll
    for (int i = 0; i < 16; ++i) acc[i] += W[(r0 + i) * LDP + k] * qv;
  }
  #pragma unroll
  for (int i = 0; i < 16; ++i) dst[(r0 + i) * NN + lane] = acc[i];

  #undef TF
  #undef FF
}

extern "C" void kernel_launch(void* const* d_in, const int* in_sizes, int n_in,
                              void* d_out, int out_size, void* d_ws, size_t ws_size,
                              hipStream_t stream) {
  const float* x = (const float*)d_in[0];
  float* out = (float*)d_out;
  float* ws = (float*)d_ws;  // nmat*64*64*4 B = 64 MB dense T handoff
  const int nmat = in_sizes[0] / (NN * NN);  // 4096
  hess64_kernel<<<nmat, 64, 0, stream>>>(x, out, ws);
  qr64_kernel<<<nmat, 64, 0, stream>>>(out, ws);
  parlett64_kernel<<<nmat, 256, 0, stream>>>(ws, out);
}

// Round 5
// 7952.440 us; speedup vs baseline: 1.0090x; 1.0090x over previous
//
#include <hip/hip_runtime.h>

#define NN 64
#define LDP (NN + 1)  // +1 padding: kills the 32/64-way column-access bank conflicts

// Deflation tolerance: float-storage T has a subdiagonal noise floor of
// ~1.2e-7 * local scale; 5e-7 is ~4x above it (proven R1-R3: absmax 0.03125).
#define DEFL_TOL 5e-7

// Packed upper-Hessenberg band with 3 subdiagonals. Row r stores cols
// max(0,r-3)..63. 2266 floats = 9064 B.
#define BAND_SIZE 2266

__device__ __forceinline__ int rb_of(int r) {
  int t = (r >= 4) ? (((r - 4) * (r - 3)) >> 1) : 0;
  int s = (r >= 3) ? (r - 3) : 0;
  return 64 * r - t - s;
}

__device__ __forceinline__ double guard_d(double p) {
  if (fabs(p) < 1e-280) return (p >= 0.0) ? 1e-280 : -1e-280;
  return p;
}

// Wave-uniform lane read of a double via v_readlane (no LDS, no lgkmcnt).
__device__ __forceinline__ double readlane_d(double v, int l) {
  union { double d; int i[2]; } u;
  u.d = v;
  int a = __builtin_amdgcn_readlane(u.i[0], l);
  int b = __builtin_amdgcn_readlane(u.i[1], l);
  union { double d; int i[2]; } w;
  w.i[0] = a; w.i[1] = b;
  return w.d;
}

// Single-wave workgroup fences (R3-proven). lgkmcnt(0) + clobber for
// cross-lane LDS visibility; sched_barrier stops hoisting (rule #18).
#define WAVE_FENCE()                                   \
  do {                                                 \
    asm volatile("s_waitcnt lgkmcnt(0)" ::: "memory"); \
    __builtin_amdgcn_sched_barrier(0);                 \
  } while (0)
#define VM_FENCE()                                     \
  do {                                                 \
    asm volatile("s_waitcnt vmcnt(0)" ::: "memory");   \
    __builtin_amdgcn_sched_barrier(0);                 \
  } while (0)

// ============================================================================
// Kernel 1: Hessenberg reduction (R3-proven, unchanged). FLOAT-storage T in
// LDS, DOUBLE math. Q (transposed layout Qg[c*64+r]=Q[r][c]) built in d_out.
// ============================================================================
__global__ __launch_bounds__(64) void hess64_kernel(const float* __restrict__ x,
                                                    float* __restrict__ out,
                                                    float* __restrict__ ws) {
  __shared__ float Td[NN][LDP];
  __shared__ double vbuf[NN];

  const int lane = threadIdx.x;
  const size_t mat = blockIdx.x;
  const float* src = x + mat * NN * NN;
  float* Qg = out + mat * NN * NN;
  float* Tg = ws + mat * NN * NN;

  for (int r = 0; r < NN; ++r) Td[r][lane] = src[r * NN + lane];
  for (int c = 0; c < NN; ++c) Qg[c * NN + lane] = (c == lane) ? 1.0f : 0.0f;
  WAVE_FENCE();

  for (int k = 0; k <= NN - 3; ++k) {
    const int m = NN - 1 - k;
    double xt = (lane < m) ? (double)Td[k + 1 + lane][k] : 0.0;
    double ss = xt * xt;
    #pragma unroll
    for (int off = 32; off; off >>= 1) ss += __shfl_xor(ss, off);
    double x0 = (double)Td[k + 1][k];
    if (ss > 1e-280) {  // uniform across wave
      double sg = sqrt(ss);
      double beta = (x0 >= 0.0) ? -sg : sg;
      double tau = 1.0 / (ss - beta * x0);
      vbuf[lane] = (lane < m) ? (xt - ((lane == 0) ? beta : 0.0)) : 0.0;
      WAVE_FENCE();
      if (lane >= k + 1) {  // left apply
        const int j = lane;
        double acc = 0.0;
        for (int t = 0; t < m; ++t) acc += vbuf[t] * (double)Td[k + 1 + t][j];
        acc *= tau;
        for (int t = 0; t < m; ++t)
          Td[k + 1 + t][j] = (float)((double)Td[k + 1 + t][j] - vbuf[t] * acc);
      }
      WAVE_FENCE();
      if (lane == 0) Td[k + 1][k] = (float)beta;
      if (lane >= 1 && lane < m) Td[k + 1 + lane][k] = 0.0f;
      VM_FENCE();  // Q RMW across iterations
      {  // right apply on T (LDS) and Q (global, coalesced, DOUBLE math)
        const int r = lane;
        double acc = 0.0;
        double qa = 0.0;
        for (int t = 0; t < m; ++t) {
          double vt = vbuf[t];
          acc += (double)Td[r][k + 1 + t] * vt;
          qa += (double)Qg[(k + 1 + t) * NN + r] * vt;
        }
        acc *= tau;
        qa *= tau;
        for (int t = 0; t < m; ++t) {
          double vt = vbuf[t];
          Td[r][k + 1 + t] = (float)((double)Td[r][k + 1 + t] - acc * vt);
          Qg[(k + 1 + t) * NN + r] =
              (float)((double)Qg[(k + 1 + t) * NN + r] - qa * vt);
        }
      }
      WAVE_FENCE();
    }
  }

  for (int r = 0; r < NN; ++r) Tg[r * NN + lane] = Td[r][lane];
}

// ============================================================================
// Kernel 2: Francis double-shift QR on packed band.
// R5 = R3-proven DOUBLE-math chase (R4's all-float chase FAILED: the bulge
// handoff column must stay double — float applies + float handoff degraded
// shifts; un-converged forced deflations gave absmax 0.695) + the two safe
// R4 pieces kept:
//   (a) hoisted band bases (myrb per-lane once; rbk/rbk1/rbk2 uniform/step).
//   (c) chunked 16-deep prefetch in the deferred-Q apply — R3's 1-deep
//       prefetch left a serial ~500cy/column global-latency chain, which
//       consumed the fence-removal savings (the R3 null). Q apply math stays
//       DOUBLE (R3-proven); only the loads are float, promoted on use.
// ============================================================================
#define TD(r, c) band[rb_of(r) + (c)]

__global__ __launch_bounds__(64) void qr64_kernel(float* __restrict__ out,
                                                  float* __restrict__ ws) {
  __shared__ float band[BAND_SIZE];
  __shared__ float recT[NN], recY[NN], recZ[NN];  // normalized reflector stash

  const int lane = threadIdx.x;
  const int myrb = rb_of(lane);                          // per-lane row base
  const int myrb_m1 = (lane >= 1) ? rb_of(lane - 1) : 0; // row above's base
  const size_t mat = blockIdx.x;
  float* Qg = out + mat * NN * NN;
  float* Tg = ws + mat * NN * NN;

  // dense H -> band
  for (int r = 0; r < NN; ++r) {
    int st = (r >= 3) ? (r - 3) : 0;
    if (lane >= st) band[rb_of(r) + lane] = Tg[r * NN + lane];
  }
  WAVE_FENCE();

  int hi = NN - 1;
  int its = 0, total = 0;
  while (hi > 0) {
    bool small = false;
    if (lane >= 1 && lane <= hi) {
      double s = fabs((double)band[myrb_m1 + lane - 1]) + fabs((double)band[myrb + lane]);
      if (s == 0.0) s = 1e-300;
      small = fabs((double)band[myrb + lane - 1]) <= DEFL_TOL * s;
    }
    unsigned long long msk = __ballot(small) | 1ULL;
    if (hi < 63) msk &= (2ULL << hi) - 1ULL;
    const int lo = 63 - __clzll(msk);
    if (lo > 0) {
      if (lane == 0) TD(lo, lo - 1) = 0.0f;
      WAVE_FENCE();
    }
    if (lo == hi) { hi -= 1; its = 0; continue; }
    if (lo == hi - 1) {  // 2x2 window (cold path)
      double a = TD(hi - 1, hi - 1), b = TD(hi - 1, hi);
      double c = TD(hi, hi - 1), d = TD(hi, hi);
      double pp = 0.5 * (a - d);
      double disc = pp * pp + b * c;
      if (disc >= 0.0) {  // real pair: rotate to triangular
        double sq = sqrt(disc);
        double mid = 0.5 * (a + d);
        double lam = mid + ((mid >= 0.0) ? sq : -sq);
        double u0 = b, u1 = lam - a;
        double w0 = lam - d, w1 = c;
        double nu = u0 * u0 + u1 * u1, nw = w0 * w0 + w1 * w1;
        double cs, sn;
        if (nu >= nw && nu > 1e-280) { double n2 = sqrt(nu); cs = u0 / n2; sn = u1 / n2; }
        else if (nw > 1e-280) { double n2 = sqrt(nw); cs = w0 / n2; sn = w1 / n2; }
        else { cs = 1.0; sn = 0.0; }
        {
          const int j = lane;
          const int jmin = (hi >= 2) ? (hi - 2) : 0;  // cols < hi-2 exact 0
          if (j >= jmin) {
            double r0 = TD(hi - 1, j), r1 = TD(hi, j);
            TD(hi - 1, j) = (float)(cs * r0 + sn * r1);
            TD(hi, j) = (float)(cs * r1 - sn * r0);
          }
        }
        WAVE_FENCE();
        {
          const int r = lane;
          if (r <= hi) {
            double c0 = TD(r, hi - 1), c1 = TD(r, hi);
            TD(r, hi - 1) = (float)(cs * c0 + sn * c1);
            TD(r, hi) = (float)(cs * c1 - sn * c0);
          }
        }
        VM_FENCE();  // drain prior deferred-Q stores before Q RMW
        {
          const int r = lane;
          double q0 = (double)Qg[(hi - 1) * NN + r], q1 = (double)Qg[hi * NN + r];
          Qg[(hi - 1) * NN + r] = (float)(cs * q0 + sn * q1);
          Qg[hi * NN + r] = (float)(cs * q1 - sn * q0);
        }
        WAVE_FENCE();
        if (lane == 0) TD(hi, hi - 1) = 0.0f;
        WAVE_FENCE();
      }
      hi -= 2; its = 0; continue;
    }
    ++its; ++total;
    if (its > 40 || total > 2000) {  // safety: force deflation
      if (lane == 0) TD(hi, hi - 1) = 0.0f;
      WAVE_FENCE();
      hi -= 1; its = 0; continue;
    }
    double sa, sb, sc2, sd2;
    if (its == 10 || its == 20 || its == 30) {  // exceptional shift
      double sx = fabs((double)TD(hi, hi - 1)) + fabs((double)TD(hi - 1, hi - 2));
      sa = 0.75 * sx + (double)TD(hi, hi); sb = -0.4375 * sx; sc2 = sx; sd2 = sa;
    } else {
      sa = TD(hi - 1, hi - 1); sb = TD(hi - 1, hi);
      sc2 = TD(hi, hi - 1); sd2 = TD(hi, hi);
    }
    double tr = sa + sd2;
    double det = sa * sd2 - sb * sc2;
    double h11 = TD(lo, lo), h12 = TD(lo, lo + 1), h21 = TD(lo + 1, lo);
    double h22 = TD(lo + 1, lo + 1), h32 = TD(lo + 2, lo + 1);
    double cvx = h11 * h11 + h12 * h21 - tr * h11 + det;
    double cvy = h21 * (h11 + h22 - tr);
    double cvz = h21 * h32;

    int nk = hi - lo;  // reflectors recorded this sweep (uniform register)
    for (int k = lo; k <= hi - 1; ++k) {  // bulge chase — T only, DOUBLE math
      const int rbk = rb_of(k), rbk1 = rb_of(k + 1), rbk2 = rb_of(k + 2);
      const int nr = (k + 2 <= hi) ? 3 : 2;
      const double vx = cvx, vy = cvy, vz = (nr == 3) ? cvz : 0.0;
      double ss2 = vx * vx + vy * vy + vz * vz;
      if (ss2 < 1e-280) { nk = k - lo; break; }  // bulge collapsed
      double sg = sqrt(ss2);
      double beta = (vx >= 0.0) ? -sg : sg;
      double v0 = vx - beta, v1 = vy, v2 = vz;
      double tau = 1.0 / (ss2 - beta * vx);
      if (lane == 0) {  // stash normalized reflector (uniform, O(1)-bounded)
        double iv0 = 1.0 / v0;  // |v0| >= sg > 0 here
        recT[k - lo] = (float)(tau * v0 * v0);
        recY[k - lo] = (float)(v1 * iv0);
        recZ[k - lo] = (float)(v2 * iv0);
      }
      const int jlo = (k > lo) ? k : lo;
      if (lane >= jlo) {  // left apply
        const int j = lane;
        double t0 = band[rbk + j], t1 = band[rbk1 + j];
        double t2v = (nr == 3) ? (double)band[rbk2 + j] : 0.0;
        double tt = tau * (v0 * t0 + v1 * t1 + v2 * t2v);
        band[rbk + j] = (float)(t0 - v0 * tt);
        band[rbk1 + j] = (float)(t1 - v1 * tt);
        if (nr == 3) band[rbk2 + j] = (float)(t2v - v2 * tt);
      }
      WAVE_FENCE();
      if (lane == 0 && k > lo) {  // exact bulge zeros (col k-1)
        band[rbk + (k - 1)] = (float)beta;
        band[rbk1 + (k - 1)] = 0.0f;
        if (nr == 3) band[rbk2 + (k - 1)] = 0.0f;
      }
      const int rmax = (k + 3 <= hi) ? (k + 3) : hi;
      double n0 = 0.0, n1 = 0.0, n2 = 0.0;
      if (lane <= rmax) {  // right apply
        double c0 = band[myrb + k], c1 = band[myrb + k + 1];
        double c2v = (nr == 3) ? (double)band[myrb + k + 2] : 0.0;
        double tt = tau * (c0 * v0 + c1 * v1 + c2v * v2);
        n0 = c0 - tt * v0;
        n1 = c1 - tt * v1;
        n2 = c2v - tt * v2;
      }
      {  // register handoff of next bulge column (DOUBLE, never rounded)
        const int ly = (k + 2 <= 63) ? (k + 2) : 0;
        const int lz = (k + 3 <= hi) ? (k + 3) : 0;
        cvx = readlane_d(n0, k + 1);
        cvy = readlane_d(n0, ly);
        cvz = readlane_d(n0, lz);
      }
      if (lane <= rmax) {
        band[myrb + k] = (float)n0;
        band[myrb + k + 1] = (float)n1;
        if (nr == 3) band[myrb + k + 2] = (float)n2;
      }
      WAVE_FENCE();
    }

    // ---- deferred Q apply: chunked 16-deep prefetch, DOUBLE math (R3) ----
    VM_FENCE();  // drain prior sweep's Q stores before reloading
    {
      double qw0 = (double)Qg[lo * NN + lane];
      double qw1 = (double)Qg[(lo + 1) * NN + lane];
      double qw2 = (double)Qg[(lo + 2) * NN + lane];
      int done = 0;
      while (done < nk) {
        const int cnt = (nk - done < 16) ? (nk - done) : 16;
        float p[16];
        #pragma unroll
        for (int u = 0; u < 16; ++u) {  // issue all chunk loads together
          const int kc = lo + done + u + 3;
          p[u] = (u < cnt && kc <= hi) ? Qg[kc * NN + lane] : 0.0f;
        }
        #pragma unroll
        for (int u = 0; u < 16; ++u) {
          if (u < cnt) {
            const int i = done + u;
            const double tq = (double)recT[i];
            const double r1 = (double)recY[i];
            const double r2 = (double)recZ[i];
            const double t = tq * (qw0 + qw1 * r1 + qw2 * r2);
            qw0 -= t;
            qw1 -= t * r1;
            qw2 -= t * r2;
            Qg[(lo + i) * NN + lane] = (float)qw0;  // col lo+i final
            qw0 = qw1; qw1 = qw2; qw2 = (double)p[u];
          }
        }
        done += 16;
      }
      if (nk == hi - lo) {
        Qg[hi * NN + lane] = (float)qw0;  // flush last window col
      } else {  // collapsed at k = lo+nk: flush pending window cols
        const int k = lo + nk;
        Qg[k * NN + lane] = (float)qw0;
        Qg[(k + 1) * NN + lane] = (float)qw1;
        if (k + 2 <= hi) Qg[(k + 2) * NN + lane] = (float)qw2;
      }
    }
  }
  WAVE_FENCE();

  // band -> dense Schur T (subdiag + upper only)
  for (int r = 0; r < NN; ++r) {
    float v = 0.0f;
    int st = (r >= 1) ? (r - 1) : 0;
    if (lane >= st) v = band[rb_of(r) + lane];
    Tg[r * NN + lane] = v;
  }
}

// ============================================================================
// Kernel 3: Parlett recurrence + symmetrize + Q Fs Q^T (R2/R3-proven,
// unchanged). 256 threads, 4-thread group per Sylvester pair.
// ============================================================================
__global__ __launch_bounds__(256) void parlett64_kernel(const float* __restrict__ ws,
                                                        float* __restrict__ out) {
  __shared__ float Tfbuf[NN * LDP];
  __shared__ float Fbuf[NN * LDP];
  __shared__ int blkstart[NN];
  __shared__ int bi_of[NN];
  float* Tf = Tfbuf;
  float* Fp = Fbuf;

  const int tid = threadIdx.x;
  const int w = tid >> 6;
  const int lane = tid & 63;
  const size_t mat = blockIdx.x;
  const float* Tg = ws + mat * NN * NN;
  float* dst = out + mat * NN * NN;
  float* Qg = dst;

  #define TF(r, c) ((double)Tf[(r) * LDP + (c)])
  #define FF(r, c) Fp[(r) * LDP + (c)]

  for (int r = w; r < NN; r += 4) Tf[r * LDP + lane] = Tg[r * NN + lane];
  __syncthreads();

  unsigned long long pair_mask =
      __ballot((lane < NN - 1) && (Tf[(lane + 1) * LDP + lane] != 0.0f));
  unsigned long long start_mask = ~(pair_mask << 1);
  const bool isstart = (start_mask >> lane) & 1ULL;
  const bool ispair = (pair_mask >> lane) & 1ULL;
  double fdiag = 0.0, mymod = 1e300;
  if (isstart) {
    if (ispair) {
      double a = TF(lane, lane), b = TF(lane, lane + 1);
      double c = TF(lane + 1, lane), d = TF(lane + 1, lane + 1);
      fdiag = sqrt(fmax(a * d - b * c, 0.0));
    } else {
      fdiag = fabs(TF(lane, lane));
    }
    mymod = fdiag;
  }
  #pragma unroll
  for (int off = 32; off; off >>= 1) mymod = fmin(mymod, __shfl_xor(mymod, off));
  const double cshift = 1e-6 * mymod;

  if (tid < NN) {
    int nb = (int)__popcll(start_mask & ((1ULL << lane) - 1ULL));
    bi_of[lane] = nb;
    if (isstart) blkstart[nb] = lane;
  }
  for (int r = w; r < NN; r += 4) FF(r, lane) = 0.0f;
  __syncthreads();
  if (tid < NN && isstart) {
    FF(lane, lane) = (float)fdiag;
    if (ispair) FF(lane + 1, lane + 1) = (float)fdiag;
  }
  __syncthreads();

  const int sub = lane & 3;
  const int si = (lane & ~3) | w;

  for (int dist = 1; dist < NN; ++dist) {
    const int sj = si + dist;
    bool active = (sj < NN) && ((start_mask >> si) & 1ULL) && ((start_mask >> sj) & 1ULL);
    if (active) {
      const int p = ((pair_mask >> si) & 1ULL) ? 2 : 1;
      const int q = ((pair_mask >> sj) & 1ULL) ? 2 : 1;
      const int bi0 = bi_of[si], bi1 = bi_of[sj];
      double c00 = 0, c01 = 0, c10 = 0, c11 = 0;
      for (int b = bi0 + sub; b < bi1; b += 4) {
        const int k = blkstart[b];
        const bool kp = (pair_mask >> k) & 1ULL;
        double f00 = FF(si, k);
        double f01 = kp ? (double)FF(si, k + 1) : 0.0;
        double f10 = (p == 2) ? (double)FF(si + 1, k) : 0.0;
        double f11 = (p == 2 && kp) ? (double)FF(si + 1, k + 1) : 0.0;
        double t00 = TF(k, sj);
        double t01 = (q == 2) ? TF(k, sj + 1) : 0.0;
        double t10 = kp ? TF(k + 1, sj) : 0.0;
        double t11 = (kp && q == 2) ? TF(k + 1, sj + 1) : 0.0;
        c00 += f00 * t00 + f01 * t10;
        c01 += f00 * t01 + f01 * t11;
        c10 += f10 * t00 + f11 * t10;
        c11 += f10 * t01 + f11 * t11;
      }
      for (int b = bi0 + 1 + sub; b <= bi1; b += 4) {
        const int k = blkstart[b];
        const bool kp = (pair_mask >> k) & 1ULL;
        double t00 = TF(si, k);
        double t01 = kp ? TF(si, k + 1) : 0.0;
        double t10 = (p == 2) ? TF(si + 1, k) : 0.0;
        double t11 = (p == 2 && kp) ? TF(si + 1, k + 1) : 0.0;
        double f00 = FF(k, sj);
        double f01 = (q == 2) ? (double)FF(k, sj + 1) : 0.0;
        double f10 = kp ? (double)FF(k + 1, sj) : 0.0;
        double f11 = (kp && q == 2) ? (double)FF(k + 1, sj + 1) : 0.0;
        c00 -= t00 * f00 + t01 * f10;
        c01 -= t00 * f01 + t01 * f11;
        c10 -= t10 * f00 + t11 * f10;
        c11 -= t10 * f01 + t11 * f11;
      }
      c00 += __shfl_xor(c00, 1); c00 += __shfl_xor(c00, 2);
      c01 += __shfl_xor(c01, 1); c01 += __shfl_xor(c01, 2);
      c10 += __shfl_xor(c10, 1); c10 += __shfl_xor(c10, 2);
      c11 += __shfl_xor(c11, 1); c11 += __shfl_xor(c11, 2);
      if (sub == 0) {
        double x00 = 0, x01 = 0, x10 = 0, x11 = 0;
        if (p == 1 && q == 1) {
          x00 = c00 / guard_d(TF(si, si) - TF(sj, sj));
        } else if (p == 2 && q == 1) {
          double t = TF(sj, sj);
          double m00 = TF(si, si) - t, m01 = TF(si, si + 1);
          double m10 = TF(si + 1, si), m11 = TF(si + 1, si + 1) - t;
          double dd = guard_d(m00 * m11 - m01 * m10);
          x00 = (m11 * c00 - m01 * c10) / dd;
          x10 = (m00 * c10 - m10 * c00) / dd;
        } else if (p == 1 && q == 2) {
          double t = TF(si, si);
          double m00 = t - TF(sj, sj), m01 = -TF(sj, sj + 1);
          double m10 = -TF(sj + 1, sj), m11 = t - TF(sj + 1, sj + 1);
          double dd = guard_d(m00 * m11 - m01 * m10);
          x00 = (c00 * m11 - c01 * m10) / dd;
          x01 = (c01 * m00 - c00 * m01) / dd;
        } else {
          double A00 = TF(si, si), A01 = TF(si, si + 1);
          double A10 = TF(si + 1, si), A11 = TF(si + 1, si + 1);
          double B00 = TF(sj, sj), B01 = TF(sj, sj + 1);
          double B10 = TF(sj + 1, sj), B11 = TF(sj + 1, sj + 1);
          double M[4][5] = {
              {A00 - B00, A01, -B10, 0.0, c00},
              {A10, A11 - B00, 0.0, -B10, c10},
              {-B01, 0.0, A00 - B11, A01, c01},
              {0.0, -B01, A10, A11 - B11, c11}};
          #pragma unroll
          for (int cc = 0; cc < 4; ++cc) {
            #pragma unroll
            for (int rr2 = cc + 1; rr2 < 4; ++rr2) {
              bool sw = fabs(M[rr2][cc]) > fabs(M[cc][cc]);
              #pragma unroll
              for (int t2 = cc; t2 < 5; ++t2) {
                double aa = M[cc][t2], bb = M[rr2][t2];
                M[cc][t2] = sw ? bb : aa;
                M[rr2][t2] = sw ? aa : bb;
              }
            }
            double inv = 1.0 / guard_d(M[cc][cc]);
            #pragma unroll
            for (int rr2 = cc + 1; rr2 < 4; ++rr2) {
              double f2 = M[rr2][cc] * inv;
              #pragma unroll
              for (int t2 = cc; t2 < 5; ++t2) M[rr2][t2] -= f2 * M[cc][t2];
            }
          }
          double z3 = M[3][4] / guard_d(M[3][3]);
          double z2 = (M[2][4] - M[2][3] * z3) / guard_d(M[2][2]);
          double z1 = (M[1][4] - M[1][3] * z3 - M[1][2] * z2) / guard_d(M[1][1]);
          double z0 = (M[0][4] - M[0][3] * z3 - M[0][2] * z2 - M[0][1] * z1) / guard_d(M[0][0]);
          x00 = z0; x10 = z1; x01 = z2; x11 = z3;
        }
        FF(si, sj) = (float)x00;
        if (q == 2) FF(si, sj + 1) = (float)x01;
        if (p == 2) {
          FF(si + 1, sj) = (float)x10;
          if (q == 2) FF(si + 1, sj + 1) = (float)x11;
        }
      }
    }
    __syncthreads();
  }

  {
    const int r = lane;
    for (int j = r + 1 + w; j < NN; j += 4) {
      float v = 0.5f * (FF(r, j) + FF(j, r));
      FF(r, j) = v;
      FF(j, r) = v;
    }
    if (w == 0) FF(r, r) += (float)cshift;
  }
  __syncthreads();

  float* Qs = Tf;  // T dead after Parlett
  for (int c = w; c < NN; c += 4) Qs[lane * LDP + c] = Qg[c * NN + lane];
  __syncthreads();

  float acc[16];
  const int r0 = w * 16;
  #pragma unroll
  for (int i = 0; i < 16; ++i) acc[i] = 0.0f;
  for (int k = 0; k < NN; ++k) {
    float f = FF(k, lane);
    #pragma unroll
    for (int i = 0; i < 16; ++i) acc[i] += Qs[(r0 + i) * LDP + k] * f;
  }
  __syncthreads();
  float* W = Fp;
  #pragma unroll
  for (int i = 0; i < 16; ++i) W[(r0 + i) * LDP + lane] = acc[i];
  __syncthreads();

  #pragma unroll
  for (int i = 0; i < 16; ++i) acc[i] = 0.0f;
  for (int k = 0; k < NN; ++k) {
    float qv = Qs[lane * LDP + k];
    #pragma unroll
    for (int i = 0; i < 16; ++i) acc[i] += W[(r0 + i) * LDP + k] * qv;
  }
  #pragma unroll
  for (int i = 0; i < 16; ++i) dst[(r0 + i) * NN + lane] = acc[i];

  #undef TF
  #undef FF
}

extern "C" void kernel_launch(void* const* d_in, const int* in_sizes, int n_in,
                              void* d_out, int out_size, void* d_ws, size_t ws_size,
                              hipStream_t stream) {
  const float* x = (const float*)d_in[0];
  float* out = (float*)d_out;
  float* ws = (float*)d_ws;  // nmat*64*64*4 B = 64 MB dense T handoff
  const int nmat = in_sizes[0] / (NN * NN);  // 4096
  hess64_kernel<<<nmat, 64, 0, stream>>>(x, out, ws);
  qr64_kernel<<<nmat, 64, 0, stream>>>(out, ws);
  parlett64_kernel<<<nmat, 256, 0, stream>>>(ws, out);
}